// Round 7
// baseline (383.706 us; speedup 1.0000x reference)
//
#include <hip/hip_runtime.h>
#include <math.h>

#define H    128
#define TT   128
#define CH   8            // timesteps per B-block

// ws float offsets (total ~5.8 MB of d_ws)
#define OFF_H1V   0                 // [b][t][256]  h1 | v          : 262144 floats
#define OFF_PARTS 262144            // [b][t][1024] z2 | ad         : 1048576 floats
#define OFF_GPART 1310720           // [b][t][128]  unreduced g     : 131072 floats

__device__ __forceinline__ float sigf(float x)       { return 1.0f / (1.0f + __expf(-x)); }
__device__ __forceinline__ float tanhf_fast(float x) { return 1.0f - 2.0f / (1.0f + __expf(2.0f * x)); }

// sum over the 4-lane p-group via DPP quad_perm (VALU, no LDS traffic)
__device__ __forceinline__ float quad_sum(float v) {
    int t = __builtin_amdgcn_update_dpp(0, __float_as_int(v), 0xB1, 0xF, 0xF, true); // xor 1
    v += __int_as_float(t);
    t = __builtin_amdgcn_update_dpp(0, __float_as_int(v), 0x4E, 0xF, 0xF, true);     // xor 2
    v += __int_as_float(t);
    return v;
}

// Load one float4 of weights, pin scalars in the register file (no remat loads).
#define DECLW4(nm, src) \
    float4 _t_##nm = (src); \
    float nm##_x = _t_##nm.x, nm##_y = _t_##nm.y, nm##_z = _t_##nm.z, nm##_w = _t_##nm.w; \
    asm volatile("" : "+v"(nm##_x), "+v"(nm##_y), "+v"(nm##_z), "+v"(nm##_w));

// Gate-aligned weight residency: thread (rg,p) holds rows {rg,rg+128,rg+256,rg+384},
// k-slice [32p, 32p+32) -> 128 floats/thread.
#define LOADW_ALL(W) \
    const float4* wpa_ = (const float4*)((W) + (size_t)(rg)       * H + p * 32); \
    const float4* wpb_ = (const float4*)((W) + (size_t)(rg + 128) * H + p * 32); \
    const float4* wpc_ = (const float4*)((W) + (size_t)(rg + 256) * H + p * 32); \
    const float4* wpd_ = (const float4*)((W) + (size_t)(rg + 384) * H + p * 32); \
    DECLW4(wa0, wpa_[0]) DECLW4(wa1, wpa_[1]) DECLW4(wa2, wpa_[2]) DECLW4(wa3, wpa_[3]) \
    DECLW4(wa4, wpa_[4]) DECLW4(wa5, wpa_[5]) DECLW4(wa6, wpa_[6]) DECLW4(wa7, wpa_[7]) \
    DECLW4(wb0, wpb_[0]) DECLW4(wb1, wpb_[1]) DECLW4(wb2, wpb_[2]) DECLW4(wb3, wpb_[3]) \
    DECLW4(wb4, wpb_[4]) DECLW4(wb5, wpb_[5]) DECLW4(wb6, wpb_[6]) DECLW4(wb7, wpb_[7]) \
    DECLW4(wc0, wpc_[0]) DECLW4(wc1, wpc_[1]) DECLW4(wc2, wpc_[2]) DECLW4(wc3, wpc_[3]) \
    DECLW4(wc4, wpc_[4]) DECLW4(wc5, wpc_[5]) DECLW4(wc6, wpc_[6]) DECLW4(wc7, wpc_[7]) \
    DECLW4(wd0, wpd_[0]) DECLW4(wd1, wpd_[1]) DECLW4(wd2, wpd_[2]) DECLW4(wd3, wpd_[3]) \
    DECLW4(wd4, wpd_[4]) DECLW4(wd5, wpd_[5]) DECLW4(wd6, wpd_[6]) DECLW4(wd7, wpd_[7])

#define FMA1(nm, ov, acc) \
    acc = fmaf(nm##_x, ov.x, acc); acc = fmaf(nm##_y, ov.y, acc); \
    acc = fmaf(nm##_z, ov.z, acc); acc = fmaf(nm##_w, ov.w, acc);

#define DOTJ(j) FMA1(wa##j, hv##j, a0) FMA1(wb##j, hv##j, a1) FMA1(wc##j, hv##j, a2) FMA1(wd##j, hv##j, a3)

// 8 b128 broadcast reads + 128 FMA + quad reduction -> a0..a3 = full gate dots
#define DOT_BODY(HBASE) \
    const float4* _hp4 = (const float4*)(HBASE); \
    float4 hv0=_hp4[0],hv1=_hp4[1],hv2=_hp4[2],hv3=_hp4[3], \
           hv4=_hp4[4],hv5=_hp4[5],hv6=_hp4[6],hv7=_hp4[7]; \
    float a0=0.f,a1=0.f,a2=0.f,a3=0.f; \
    DOTJ(0) DOTJ(1) DOTJ(2) DOTJ(3) DOTJ(4) DOTJ(5) DOTJ(6) DOTJ(7) \
    a0 = quad_sum(a0); a1 = quad_sum(a1); a2 = quad_sum(a2); a3 = quad_sum(a3);

// ---------------------------------------------------------------------------
// Phase A: layer-1 recurrence, one block per batch. Writes h1[t], v[t].
// ---------------------------------------------------------------------------
__global__ __launch_bounds__(512, 1)
void akernel(const float* __restrict__ x,
             const float* __restrict__ w_ih0,
             const float* __restrict__ w_hh0,
             const float* __restrict__ b_ih0,
             const float* __restrict__ b_hh0,
             float* __restrict__ ws) {
    const int b  = blockIdx.x;
    const int r  = threadIdx.x;
    const int rg = r >> 2, p = r & 3;
    const int wsl = rg >> 5, wpos = rg & 31;
    float* h1v = ws + OFF_H1V + (size_t)b * TT * 256;

    __shared__ float hbuf[2][144];    // h1 state, 4 padded slices x 36
    __shared__ float u_s[TT];
    __shared__ float scr[512];

    LOADW_ALL(w_hh0)
    const float b0 = b_ih0[rg]       + b_hh0[rg];
    const float b1 = b_ih0[rg + 128] + b_hh0[rg + 128];
    const float b2 = b_ih0[rg + 256] + b_hh0[rg + 256];
    const float b3 = b_ih0[rg + 384] + b_hh0[rg + 384];
    const float wi0 = w_ih0[rg], wi1 = w_ih0[rg + 128];
    const float wi2 = w_ih0[rg + 256], wi3 = w_ih0[rg + 384];
    {   // u[t] = trace(x[b,t]) cooperatively (4 partials per t)
        const float* xb = x + (size_t)(b * TT + (r & 127)) * 1024;
        const int pq = r >> 7;
        float u = 0.f;
#pragma unroll
        for (int i = 0; i < 8; i++) u += xb[(pq * 8 + i) * 33];
        scr[r] = u;
    }
    if (r < 144) hbuf[0][r] = 0.f;
    __syncthreads();
    if (r < TT) u_s[r] = scr[r] + scr[r + 128] + scr[r + 256] + scr[r + 384];
    __syncthreads();

    float c1 = 0.f;
    for (int t = 0; t < TT; t++) {
        const float* hc = hbuf[t & 1];
        float* hx = hbuf[(t & 1) ^ 1];
        DOT_BODY(hc + p * 36)
        const float u = u_s[t];
        float z0 = a0 + fmaf(wi0, u, b0);
        float z1 = a1 + fmaf(wi1, u, b1);
        float z2 = a2 + fmaf(wi2, u, b2);
        float z3 = a3 + fmaf(wi3, u, b3);
        float gi = sigf(z0), gf = sigf(z1), gg = tanhf_fast(z2), go = sigf(z3);
        float di = gi * (1.f - gi) * wi0, df = gf * (1.f - gf) * wi1;
        float dg = (1.f - gg * gg) * wi2, dd = go * (1.f - go) * wi3;
        float dc = df * c1 + di * gg + gi * dg;
        c1 = gf * c1 + gi * gg;
        float th = tanhf_fast(c1);
        float hn = go * th;
        float vn = dd * th + go * (1.f - th * th) * dc;
        if (p == wsl) hx[p * 36 + wpos] = hn;       // one writer per h-index
        if (p == 0) h1v[t * 256 + rg] = hn;         // publish h1
        if (p == 1) h1v[t * 256 + 128 + rg] = vn;   // publish v
        __syncthreads();
    }
}

// ---------------------------------------------------------------------------
// Phase B: all w_ih1 dots — parallel over (role, batch, t-chunk). 256 blocks.
//   role 0: z2[t] = w_ih1 @ h1[t]   role 1: ad[t] = w_ih1 @ v[t]
// ---------------------------------------------------------------------------
__global__ __launch_bounds__(512, 1)
void bkernel(const float* __restrict__ w_ih1, float* __restrict__ ws) {
    const int id   = blockIdx.x;        // 0..255
    const int role = id >> 7;
    const int b    = (id >> 4) & 7;
    const int c    = id & 15;           // t-chunk
    const int r    = threadIdx.x;
    const int rg   = r >> 2, p = r & 3;

    __shared__ float hb[CH * 144];      // staged chunk, padded slices
    LOADW_ALL(w_ih1)
    const float* hsrc = ws + OFF_H1V + (size_t)b * TT * 256 + (role ? 128 : 0);
    if (r < 256) {
        int tl = r >> 5, k4 = r & 31, s = k4 >> 3, j = k4 & 7;
        float4 v = *(const float4*)(hsrc + (size_t)(c * CH + tl) * 256 + k4 * 4);
        *(float4*)&hb[(tl * 4 + s) * 36 + j * 4] = v;
    }
    __syncthreads();
    float* pbase = ws + OFF_PARTS + (size_t)b * TT * 1024 + (role ? 512 : 0);
#pragma unroll
    for (int tl = 0; tl < CH; tl++) {
        DOT_BODY(hb + (tl * 4 + p) * 36)
        // lane p stores gate-p's dot -> C reads the 4 gates back as ONE float4
        float sel = (p == 0) ? a0 : (p == 1) ? a1 : (p == 2) ? a2 : a3;
        pbase[(size_t)(c * CH + tl) * 1024 + r] = sel;
    }
}

// ---------------------------------------------------------------------------
// Phase C: layer-2 recurrence, one block per batch. Per-step output
// contribution written UNREDUCED to gpart (reduced later in fill).
// ---------------------------------------------------------------------------
__global__ __launch_bounds__(512, 1)
void ckernel(const float* __restrict__ w_hh1,
             const float* __restrict__ b_ih1,
             const float* __restrict__ b_hh1,
             const float* __restrict__ w_out,
             float* __restrict__ ws) {
    const int b  = blockIdx.x;
    const int r  = threadIdx.x;
    const int rg = r >> 2, p = r & 3;
    const int wsl = rg >> 5, wpos = rg & 31;

    __shared__ float hbuf[2][144];      // h2 state
    LOADW_ALL(w_hh1)
    const float b0 = b_ih1[rg]       + b_hh1[rg];
    const float b1 = b_ih1[rg + 128] + b_hh1[rg + 128];
    const float b2 = b_ih1[rg + 256] + b_hh1[rg + 256];
    const float b3 = b_ih1[rg + 384] + b_hh1[rg + 384];
    const float wo = w_out[rg];
    if (r < 144) hbuf[0][r] = 0.f;
    __syncthreads();

    const float* parts = ws + OFF_PARTS + (size_t)b * TT * 1024;
    float* gpart = ws + OFF_GPART + (size_t)b * TT * 128;
    float c2 = 0.f;
    for (int t = 0; t < TT; t++) {
        float4 zf = *(const float4*)(parts + (size_t)t * 1024 + rg * 4);        // early issue
        float4 af = *(const float4*)(parts + (size_t)t * 1024 + 512 + rg * 4);
        const float* hc = hbuf[t & 1];
        float* hx = hbuf[(t & 1) ^ 1];
        DOT_BODY(hc + p * 36)
        float z0 = a0 + b0 + zf.x;
        float z1 = a1 + b1 + zf.y;
        float z2 = a2 + b2 + zf.z;
        float z3 = a3 + b3 + zf.w;
        float gi = sigf(z0), gf = sigf(z1), gg = tanhf_fast(z2), go = sigf(z3);
        float di = gi * (1.f - gi) * af.x, df = gf * (1.f - gf) * af.y;
        float dg = (1.f - gg * gg) * af.z, dd = go * (1.f - go) * af.w;
        float dc = df * c2 + di * gg + gi * dg;
        c2 = gf * c2 + gi * gg;
        float th = tanhf_fast(c2);
        if (p == wsl) hx[p * 36 + wpos] = go * th;
        float dh2 = dd * th + go * (1.f - th * th) * dc;
        if (p == 0) gpart[t * 128 + rg] = wo * dh2;   // unreduced contribution
        __syncthreads();
    }
}

// ---------------------------------------------------------------------------
// fill: one block per (b,t). Reduce gpart[bt][0..127] -> g, then write the
// 32x32 diagonal block: out[b,t,i,j] = (i==j) ? g : 0.
// ---------------------------------------------------------------------------
__global__ __launch_bounds__(256)
void fill_kernel(const float* __restrict__ gpart, float4* __restrict__ out4) {
    const int bt = blockIdx.x;          // 0..1023
    const int r  = threadIdx.x;         // 0..255
    __shared__ float red[129];
    if (r < 128) red[r] = gpart[(size_t)bt * 128 + r];
    __syncthreads();
    if (r < 64) {
        float v = red[r] + red[r + 64];
#pragma unroll
        for (int s = 32; s > 0; s >>= 1) v += __shfl_down(v, s, 64);
        if (r == 0) red[128] = v;
    }
    __syncthreads();
    const float g = red[128];
    const int m  = r * 4;               // offset within the 32x32 matrix
    const int i  = m >> 5, j0 = m & 31;
    float4 v;
    v.x = (j0     == i) ? g : 0.f;
    v.y = (j0 + 1 == i) ? g : 0.f;
    v.z = (j0 + 2 == i) ? g : 0.f;
    v.w = (j0 + 3 == i) ? g : 0.f;
    out4[(size_t)bt * 256 + r] = v;
}

extern "C" void kernel_launch(void* const* d_in, const int* in_sizes, int n_in,
                              void* d_out, int out_size, void* d_ws, size_t ws_size,
                              hipStream_t stream) {
    const float* x     = (const float*)d_in[0];
    const float* w_ih0 = (const float*)d_in[1];
    const float* w_hh0 = (const float*)d_in[2];
    const float* b_ih0 = (const float*)d_in[3];
    const float* b_hh0 = (const float*)d_in[4];
    const float* w_ih1 = (const float*)d_in[5];
    const float* w_hh1 = (const float*)d_in[6];
    const float* b_ih1 = (const float*)d_in[7];
    const float* b_hh1 = (const float*)d_in[8];
    const float* w_out = (const float*)d_in[9];
    // d_in[10] = b_out: constant offset, zero derivative -> unused

    float* ws = (float*)d_ws;   // uses ~5.8 MB of d_ws; all regions fully written
                                // before read (no dependence on poison values)

    akernel<<<dim3(8),    dim3(512), 0, stream>>>(x, w_ih0, w_hh0, b_ih0, b_hh0, ws);
    bkernel<<<dim3(256),  dim3(512), 0, stream>>>(w_ih1, ws);
    ckernel<<<dim3(8),    dim3(512), 0, stream>>>(w_hh1, b_ih1, b_hh1, w_out, ws);
    fill_kernel<<<dim3(1024), dim3(256), 0, stream>>>(ws + OFF_GPART, (float4*)d_out);
}

// Round 8
// 240.285 us; speedup vs baseline: 1.5969x; 1.5969x over previous
//
#include <hip/hip_runtime.h>
#include <math.h>

#define H    128
#define TT   128
#define CH   8            // steps per chunk/flag
#define NCH  (TT / CH)    // 16

// ws float offsets (total ~5.8 MB of d_ws)
#define OFF_H1V   0                 // [b][t][256]  h1 | v      : 262144 floats
#define OFF_PARTS 262144            // [b][t][1024] z2 | ad     : 1048576 floats
#define OFF_GPART 1310720           // [b][t][128]  unreduced g : 131072 floats
#define OFF_CNT   1441792           // int counters

__device__ __forceinline__ float sigf(float x)       { return 1.0f / (1.0f + __expf(-x)); }
__device__ __forceinline__ float tanhf_fast(float x) { return 1.0f - 2.0f / (1.0f + __expf(2.0f * x)); }

// sum over the 4-lane p-group via DPP quad_perm (VALU, no LDS traffic)
__device__ __forceinline__ float quad_sum(float v) {
    int t = __builtin_amdgcn_update_dpp(0, __float_as_int(v), 0xB1, 0xF, 0xF, true); // xor 1
    v += __int_as_float(t);
    t = __builtin_amdgcn_update_dpp(0, __float_as_int(v), 0x4E, 0xF, 0xF, true);     // xor 2
    v += __int_as_float(t);
    return v;
}

// Cheap spin: RELAXED polls (no L2 invalidate storm), then ONE acquire load
// to establish the synchronizes-with edge (counter is monotone).
__device__ __forceinline__ void wait_ge(int* ptr, int val) {
    while (__hip_atomic_load(ptr, __ATOMIC_RELAXED, __HIP_MEMORY_SCOPE_AGENT) < val)
        __builtin_amdgcn_s_sleep(1);
    (void)__hip_atomic_load(ptr, __ATOMIC_ACQUIRE, __HIP_MEMORY_SCOPE_AGENT);
}

// Load one float4 of weights, pin scalars in the register file (no remat loads).
#define DECLW4(nm, src) \
    float4 _t_##nm = (src); \
    float nm##_x = _t_##nm.x, nm##_y = _t_##nm.y, nm##_z = _t_##nm.z, nm##_w = _t_##nm.w; \
    asm volatile("" : "+v"(nm##_x), "+v"(nm##_y), "+v"(nm##_z), "+v"(nm##_w));

// Gate-aligned weight residency: thread (rg,p) holds rows {rg,rg+128,rg+256,rg+384},
// k-slice [32p, 32p+32) -> 128 floats/thread.
#define LOADW_ALL(W) \
    const float4* wpa_ = (const float4*)((W) + (size_t)(rg)       * H + p * 32); \
    const float4* wpb_ = (const float4*)((W) + (size_t)(rg + 128) * H + p * 32); \
    const float4* wpc_ = (const float4*)((W) + (size_t)(rg + 256) * H + p * 32); \
    const float4* wpd_ = (const float4*)((W) + (size_t)(rg + 384) * H + p * 32); \
    DECLW4(wa0, wpa_[0]) DECLW4(wa1, wpa_[1]) DECLW4(wa2, wpa_[2]) DECLW4(wa3, wpa_[3]) \
    DECLW4(wa4, wpa_[4]) DECLW4(wa5, wpa_[5]) DECLW4(wa6, wpa_[6]) DECLW4(wa7, wpa_[7]) \
    DECLW4(wb0, wpb_[0]) DECLW4(wb1, wpb_[1]) DECLW4(wb2, wpb_[2]) DECLW4(wb3, wpb_[3]) \
    DECLW4(wb4, wpb_[4]) DECLW4(wb5, wpb_[5]) DECLW4(wb6, wpb_[6]) DECLW4(wb7, wpb_[7]) \
    DECLW4(wc0, wpc_[0]) DECLW4(wc1, wpc_[1]) DECLW4(wc2, wpc_[2]) DECLW4(wc3, wpc_[3]) \
    DECLW4(wc4, wpc_[4]) DECLW4(wc5, wpc_[5]) DECLW4(wc6, wpc_[6]) DECLW4(wc7, wpc_[7]) \
    DECLW4(wd0, wpd_[0]) DECLW4(wd1, wpd_[1]) DECLW4(wd2, wpd_[2]) DECLW4(wd3, wpd_[3]) \
    DECLW4(wd4, wpd_[4]) DECLW4(wd5, wpd_[5]) DECLW4(wd6, wpd_[6]) DECLW4(wd7, wpd_[7])

#define FMA1(nm, ov, acc) \
    acc = fmaf(nm##_x, ov.x, acc); acc = fmaf(nm##_y, ov.y, acc); \
    acc = fmaf(nm##_z, ov.z, acc); acc = fmaf(nm##_w, ov.w, acc);

#define DOTJ(j) FMA1(wa##j, hv##j, a0) FMA1(wb##j, hv##j, a1) FMA1(wc##j, hv##j, a2) FMA1(wd##j, hv##j, a3)

// 8 b128 broadcast reads + 128 FMA + quad reduction -> a0..a3 = full gate dots
#define DOT_BODY(HBASE) \
    const float4* _hp4 = (const float4*)(HBASE); \
    float4 hv0=_hp4[0],hv1=_hp4[1],hv2=_hp4[2],hv3=_hp4[3], \
           hv4=_hp4[4],hv5=_hp4[5],hv6=_hp4[6],hv7=_hp4[7]; \
    float a0=0.f,a1=0.f,a2=0.f,a3=0.f; \
    DOTJ(0) DOTJ(1) DOTJ(2) DOTJ(3) DOTJ(4) DOTJ(5) DOTJ(6) DOTJ(7) \
    a0 = quad_sum(a0); a1 = quad_sum(a1); a2 = quad_sum(a2); a3 = quad_sum(a3);

// ---------------------------------------------------------------------------
// Overlapped 4-role pipeline, one CU per (role,batch): 32 blocks.
//   role 0 = A : layer-1 recurrence (w_hh0)        -> h1[t], v[t]
//   role 1 = B1: w_ih1 @ h1 (chunked)              -> parts[.., 0:512)
//   role 2 = B2: w_ih1 @ v  (chunked)              -> parts[.., 512:1024)
//   role 3 = C : w_hh1 @ h2 + elementwise          -> gpart (unreduced)
// Roles of batch b sit at blockIdx ≡ b (mod 8) -> same XCD under round-robin
// (perf heuristic only; correctness from agent-scope release/acquire).
// ---------------------------------------------------------------------------
__global__ __launch_bounds__(512, 1)
void pipe_kernel(const float* __restrict__ x,
                 const float* __restrict__ w_ih0,
                 const float* __restrict__ w_hh0,
                 const float* __restrict__ b_ih0,
                 const float* __restrict__ b_hh0,
                 const float* __restrict__ w_ih1,
                 const float* __restrict__ w_hh1,
                 const float* __restrict__ b_ih1,
                 const float* __restrict__ b_hh1,
                 const float* __restrict__ w_out,
                 float* __restrict__ ws) {
    const int role = blockIdx.x >> 3;
    const int b    = blockIdx.x & 7;
    const int r    = threadIdx.x;
    const int rg   = r >> 2, p = r & 3;
    const int wsl  = rg >> 5, wpos = rg & 31;

    int* cntA  = (int*)ws + OFF_CNT       + b * 32;
    int* cntB1 = (int*)ws + OFF_CNT + 256 + b * 32;
    int* cntB2 = (int*)ws + OFF_CNT + 512 + b * 32;
    float* h1v = ws + OFF_H1V + (size_t)b * TT * 256;

    __shared__ float hbuf[2][144];    // recurrent state, 4 padded slices x 36
    __shared__ float u_s[TT];
    __shared__ float scr[512];
    __shared__ float hb[CH * 144];    // B chunk staging

    if (role == 0) {
        // ===================== Stage A: layer-1 recurrence =====================
        LOADW_ALL(w_hh0)
        const float b0 = b_ih0[rg]       + b_hh0[rg];
        const float b1 = b_ih0[rg + 128] + b_hh0[rg + 128];
        const float b2 = b_ih0[rg + 256] + b_hh0[rg + 256];
        const float b3 = b_ih0[rg + 384] + b_hh0[rg + 384];
        const float wi0 = w_ih0[rg], wi1 = w_ih0[rg + 128];
        const float wi2 = w_ih0[rg + 256], wi3 = w_ih0[rg + 384];
        {   // u[t] = trace(x[b,t]) cooperatively (4 partials per t)
            const float* xb = x + (size_t)(b * TT + (r & 127)) * 1024;
            const int pq = r >> 7;
            float u = 0.f;
#pragma unroll
            for (int i = 0; i < 8; i++) u += xb[(pq * 8 + i) * 33];
            scr[r] = u;
        }
        if (r < 144) hbuf[0][r] = 0.f;
        __syncthreads();
        if (r < TT) u_s[r] = scr[r] + scr[r + 128] + scr[r + 256] + scr[r + 384];
        __syncthreads();

        float c1 = 0.f;
        for (int t = 0; t < TT; t++) {
            const float* hc = hbuf[t & 1];
            float* hx = hbuf[(t & 1) ^ 1];
            DOT_BODY(hc + p * 36)
            const float u = u_s[t];
            float z0 = a0 + fmaf(wi0, u, b0);
            float z1 = a1 + fmaf(wi1, u, b1);
            float z2 = a2 + fmaf(wi2, u, b2);
            float z3 = a3 + fmaf(wi3, u, b3);
            float gi = sigf(z0), gf = sigf(z1), gg = tanhf_fast(z2), go = sigf(z3);
            float di = gi * (1.f - gi) * wi0, df = gf * (1.f - gf) * wi1;
            float dg = (1.f - gg * gg) * wi2, dd = go * (1.f - go) * wi3;
            float dc = df * c1 + di * gg + gi * dg;
            c1 = gf * c1 + gi * gg;
            float th = tanhf_fast(c1);
            float hn = go * th;
            float vn = dd * th + go * (1.f - th * th) * dc;
            if (p == wsl) hx[p * 36 + wpos] = hn;       // one writer per h-index
            if (p == 0) h1v[t * 256 + rg] = hn;         // publish h1
            if (p == 1) h1v[t * 256 + 128 + rg] = vn;   // publish v
            __syncthreads();   // drains every thread's stores (vmcnt 0) + barrier
            if ((t & (CH - 1)) == CH - 1 && r == 0)
                __hip_atomic_store(cntA, t + 1, __ATOMIC_RELEASE, __HIP_MEMORY_SCOPE_AGENT);
        }
    } else if (role == 1 || role == 2) {
        // ============ Stages B1/B2: w_ih1 @ (h1 | v), chunk-parallel ============
        LOADW_ALL(w_ih1)
        int* myCnt = (role == 2) ? cntB2 : cntB1;
        const float* hsrc = h1v + ((role == 2) ? 128 : 0);
        float* pbase = ws + OFF_PARTS + (size_t)b * TT * 1024 + ((role == 2) ? 512 : 0);
        for (int c = 0; c < NCH; c++) {
            if (r == 0) wait_ge(cntA, (c + 1) * CH);
            __syncthreads();
            if (r < 256) {   // stage chunk into padded slices
                int tl = r >> 5, k4 = r & 31, s = k4 >> 3, j = k4 & 7;
                float4 v = *(const float4*)(hsrc + (size_t)(c * CH + tl) * 256 + k4 * 4);
                *(float4*)&hb[(tl * 4 + s) * 36 + j * 4] = v;
            }
            __syncthreads();
#pragma unroll
            for (int tl = 0; tl < CH; tl++) {
                DOT_BODY(hb + (tl * 4 + p) * 36)
                // lane p stores gate-p's dot -> C reads 4 gates back as ONE float4
                float sel = (p == 0) ? a0 : (p == 1) ? a1 : (p == 2) ? a2 : a3;
                pbase[(size_t)(c * CH + tl) * 1024 + r] = sel;
            }
            __syncthreads();   // drain all stores before flag
            if (r == 0)
                __hip_atomic_store(myCnt, (c + 1) * CH, __ATOMIC_RELEASE, __HIP_MEMORY_SCOPE_AGENT);
        }
    } else {
        // ========= Stage C: w_hh1 @ h2 + layer-2 elementwise -> gpart =========
        LOADW_ALL(w_hh1)
        const float b0 = b_ih1[rg]       + b_hh1[rg];
        const float b1 = b_ih1[rg + 128] + b_hh1[rg + 128];
        const float b2 = b_ih1[rg + 256] + b_hh1[rg + 256];
        const float b3 = b_ih1[rg + 384] + b_hh1[rg + 384];
        const float wo = w_out[rg];
        if (r < 144) hbuf[0][r] = 0.f;
        __syncthreads();
        const float* parts = ws + OFF_PARTS + (size_t)b * TT * 1024;
        float* gpart = ws + OFF_GPART + (size_t)b * TT * 128;
        float c2 = 0.f;
        for (int c = 0; c < NCH; c++) {
            if (r == 0) { wait_ge(cntB1, (c + 1) * CH); wait_ge(cntB2, (c + 1) * CH); }
            __syncthreads();
            float4 zf[CH], af[CH];   // prefetch whole chunk's partials (hide L2 lat)
#pragma unroll
            for (int tl = 0; tl < CH; tl++) {
                zf[tl] = *(const float4*)(parts + (size_t)(c * CH + tl) * 1024 + rg * 4);
                af[tl] = *(const float4*)(parts + (size_t)(c * CH + tl) * 1024 + 512 + rg * 4);
            }
#pragma unroll
            for (int tl = 0; tl < CH; tl++) {
                const int t = c * CH + tl;
                const float* hc = hbuf[t & 1];
                float* hx = hbuf[(t & 1) ^ 1];
                DOT_BODY(hc + p * 36)
                float z0 = a0 + b0 + zf[tl].x;
                float z1 = a1 + b1 + zf[tl].y;
                float z2 = a2 + b2 + zf[tl].z;
                float z3 = a3 + b3 + zf[tl].w;
                float gi = sigf(z0), gf = sigf(z1), gg = tanhf_fast(z2), go = sigf(z3);
                float di = gi * (1.f - gi) * af[tl].x, df = gf * (1.f - gf) * af[tl].y;
                float dg = (1.f - gg * gg) * af[tl].z, dd = go * (1.f - go) * af[tl].w;
                float dc = df * c2 + di * gg + gi * dg;
                c2 = gf * c2 + gi * gg;
                float th = tanhf_fast(c2);
                if (p == wsl) hx[p * 36 + wpos] = go * th;
                float dh2 = dd * th + go * (1.f - th * th) * dc;
                if (p == 0) gpart[t * 128 + rg] = wo * dh2;   // unreduced
                __syncthreads();
            }
        }
    }
}

// ---------------------------------------------------------------------------
// fill: one block per (b,t). Reduce gpart[bt][0..127] -> g, then write the
// 32x32 diagonal block: out[b,t,i,j] = (i==j) ? g : 0.
// ---------------------------------------------------------------------------
__global__ __launch_bounds__(256)
void fill_kernel(const float* __restrict__ gpart, float4* __restrict__ out4) {
    const int bt = blockIdx.x;          // 0..1023
    const int r  = threadIdx.x;         // 0..255
    __shared__ float red[129];
    if (r < 128) red[r] = gpart[(size_t)bt * 128 + r];
    __syncthreads();
    if (r < 64) {
        float v = red[r] + red[r + 64];
#pragma unroll
        for (int s = 32; s > 0; s >>= 1) v += __shfl_down(v, s, 64);
        if (r == 0) red[128] = v;
    }
    __syncthreads();
    const float g = red[128];
    const int m  = r * 4;               // offset within the 32x32 matrix
    const int i  = m >> 5, j0 = m & 31;
    float4 v;
    v.x = (j0     == i) ? g : 0.f;
    v.y = (j0 + 1 == i) ? g : 0.f;
    v.z = (j0 + 2 == i) ? g : 0.f;
    v.w = (j0 + 3 == i) ? g : 0.f;
    out4[(size_t)bt * 256 + r] = v;
}

extern "C" void kernel_launch(void* const* d_in, const int* in_sizes, int n_in,
                              void* d_out, int out_size, void* d_ws, size_t ws_size,
                              hipStream_t stream) {
    const float* x     = (const float*)d_in[0];
    const float* w_ih0 = (const float*)d_in[1];
    const float* w_hh0 = (const float*)d_in[2];
    const float* b_ih0 = (const float*)d_in[3];
    const float* b_hh0 = (const float*)d_in[4];
    const float* w_ih1 = (const float*)d_in[5];
    const float* w_hh1 = (const float*)d_in[6];
    const float* b_ih1 = (const float*)d_in[7];
    const float* b_hh1 = (const float*)d_in[8];
    const float* w_out = (const float*)d_in[9];
    // d_in[10] = b_out: constant offset, zero derivative -> unused

    float* ws = (float*)d_ws;   // ~5.8 MB used; counters rely on 0xAA poison (<0 as int)

    pipe_kernel<<<dim3(32), dim3(512), 0, stream>>>(x, w_ih0, w_hh0, b_ih0, b_hh0,
                                                    w_ih1, w_hh1, b_ih1, b_hh1, w_out,
                                                    ws);
    fill_kernel<<<dim3(1024), dim3(256), 0, stream>>>(ws + OFF_GPART, (float4*)d_out);
}